// Round 11
// baseline (181.007 us; speedup 1.0000x reference)
//
#include <hip/hip_runtime.h>

#define DDIM 256
#define HDIM 128
#define KLEN 1024
#define SCL 2.8853900817779268f   // 2*log2(e): exp2(SCL*x) == e^{2x}
#define WSTR 132                  // wt row stride for 128-d half; mult of 4

// ============ Projection -> Eq/Ek = exp2(SCL * in@W) ============
// UNCHANGED from r10 (known-correct, 59 us anchor). Block = 64 rows x 64 h-half,
// 256 threads; W staged in two 33.8 KB d-halves. Grid 544.
__global__ __launch_bounds__(256) void proj_kernel(
    const float* __restrict__ queries, const float* __restrict__ keys,
    const float* __restrict__ W_q, const float* __restrict__ W_k,
    float* __restrict__ Eq, float* __restrict__ Ek)
{
    __shared__ union {
        float w[64 * WSTR];   // 33.8 KB: wt[h][d] = W[dt+d][hbase+h], d in [0,128)
        float t[64][68];      // keys transpose staging (epilogue only)
    } sm;

    int tid = threadIdx.x;
    int hg  = tid & 31;       // h index; owns hg and hg+32
    int rg  = tid >> 5;       // row-group (8 rows)
    int blk = blockIdx.x;

    const float* in; const float* W; int row0, hbase, b = 0, kc0 = 0; bool iskey;
    if (blk < 512) {
        iskey = true;
        int xcd = blk & 7, s = blk >> 3;
        b = ((s >= 32) ? 8 : 0) + xcd;
        int r = s & 31;
        kc0   = (r >> 1) * 64;
        hbase = (r & 1) << 6;
        row0  = b * KLEN + kc0;
        in = keys; W = W_k;
    } else {
        iskey = false;
        int qi = blk - 512;
        row0  = (qi >> 1) * 64;
        hbase = (qi & 1) << 6;
        in = queries; W = W_q;
    }

    const float* r0p = in + (size_t)(row0 + rg * 8) * DDIM;
    float2 acc[8];
    #pragma unroll
    for (int j = 0; j < 8; j++) acc[j] = make_float2(0.f, 0.f);

    for (int dt = 0; dt < DDIM; dt += 128) {
        __syncthreads();
        {
            int d4g = tid >> 4;            // 0..15
            int hl  = (tid & 15) << 2;     // 0..60
            #pragma unroll
            for (int i = 0; i < 2; i++) {
                int d = i * 64 + d4g * 4;
                const float* wg = W + (size_t)(dt + d) * HDIM + hbase + hl;
                float4 g0 = *(const float4*)(wg);
                float4 g1 = *(const float4*)(wg + HDIM);
                float4 g2 = *(const float4*)(wg + 2 * HDIM);
                float4 g3 = *(const float4*)(wg + 3 * HDIM);
                *(float4*)(&sm.w[(hl + 0) * WSTR + d]) = make_float4(g0.x, g1.x, g2.x, g3.x);
                *(float4*)(&sm.w[(hl + 1) * WSTR + d]) = make_float4(g0.y, g1.y, g2.y, g3.y);
                *(float4*)(&sm.w[(hl + 2) * WSTR + d]) = make_float4(g0.z, g1.z, g2.z, g3.z);
                *(float4*)(&sm.w[(hl + 3) * WSTR + d]) = make_float4(g0.w, g1.w, g2.w, g3.w);
            }
        }
        __syncthreads();

        const float* wp0 = &sm.w[(size_t)hg * WSTR];
        const float* wp1 = &sm.w[(size_t)(hg + 32) * WSTR];
        #pragma unroll 4
        for (int d0 = 0; d0 < 128; d0 += 4) {
            float4 w0 = *(const float4*)(wp0 + d0);
            float4 w1 = *(const float4*)(wp1 + d0);
            #pragma unroll
            for (int j = 0; j < 8; j++) {
                float4 a = *(const float4*)(r0p + (size_t)j * DDIM + dt + d0);
                acc[j].x = fmaf(a.x, w0.x, acc[j].x); acc[j].y = fmaf(a.x, w1.x, acc[j].y);
                acc[j].x = fmaf(a.y, w0.y, acc[j].x); acc[j].y = fmaf(a.y, w1.y, acc[j].y);
                acc[j].x = fmaf(a.z, w0.z, acc[j].x); acc[j].y = fmaf(a.z, w1.z, acc[j].y);
                acc[j].x = fmaf(a.w, w0.w, acc[j].x); acc[j].y = fmaf(a.w, w1.w, acc[j].y);
            }
        }
    }

    if (!iskey) {
        #pragma unroll
        for (int j = 0; j < 8; j++) {
            float* er = Eq + (size_t)(row0 + rg * 8 + j) * HDIM + hbase;
            er[hg]      = __builtin_amdgcn_exp2f(SCL * acc[j].x);
            er[hg + 32] = __builtin_amdgcn_exp2f(SCL * acc[j].y);
        }
    } else {
        __syncthreads();
        #pragma unroll
        for (int j = 0; j < 8; j++) {
            int kl = rg * 8 + j;
            sm.t[hg][kl]      = __builtin_amdgcn_exp2f(SCL * acc[j].x);
            sm.t[hg + 32][kl] = __builtin_amdgcn_exp2f(SCL * acc[j].y);
        }
        __syncthreads();
        float* dst = Ek + (size_t)b * HDIM * KLEN + (size_t)hbase * KLEN + kc0;
        #pragma unroll
        for (int ii = 0; ii < 4; ii++) {
            int i2 = tid + 256 * ii;
            int hh = i2 >> 4, c = (i2 & 15) << 2;
            float4 o = make_float4(sm.t[hh][c], sm.t[hh][c + 1],
                                   sm.t[hh][c + 2], sm.t[hh][c + 3]);
            *(float4*)(dst + (size_t)hh * KLEN + c) = o;
        }
    }
}

// ============ Fused scores + masked softmax + attn@V ============
// Grid 512 (XCD-swizzled) = (b, q-pair). 512 threads (8 waves).
// Phase 1 (r10 score structure): thread = 2k x 2q, normalized p -> LDS.
// Phase 2: wave = (q, k-slice of 256), lanes = d4: coalesced float4 V loads,
// p via wave-uniform b128 LDS broadcast; 4 slice-partials reduced in LDS.
// Writes d_out directly -> no p/part round-trips, no combine kernel.
__global__ __launch_bounds__(512) void attn_kernel(
    const float* __restrict__ Eq, const float* __restrict__ Ek,
    const float* __restrict__ values, const float* __restrict__ w_v,
    const int* __restrict__ valid_lens, float* __restrict__ out)
{
    __shared__ float4 eqw[HDIM];       // (eq0, eq1, -2*wv, 0)
    __shared__ float sc0[KLEN], sc1[KLEN];
    __shared__ float red0[8], red1[8];
    __shared__ float4 pb[4][2][64];    // [k-slice][q][d4] partials (8 KB)

    int tid = threadIdx.x, lane = tid & 63, wav = tid >> 6;
    int blk = blockIdx.x;
    int xcd = blk & 7, s = blk >> 3;
    int b = ((s >= 32) ? 8 : 0) + xcd;
    int qp = s & 31;
    int bq0 = b * 64 + qp * 2;
    int vlen = valid_lens[b];

    if (tid < HDIM)
        eqw[tid] = make_float4(Eq[(size_t)bq0 * HDIM + tid],
                               Eq[(size_t)(bq0 + 1) * HDIM + tid],
                               -2.0f * w_v[tid], 0.f);
    __syncthreads();

    // ---- Phase 1: scores (r10-verified structure) ----
    int k0 = tid << 1;
    float a00 = 0.f, a01 = 0.f, a10 = 0.f, a11 = 0.f;
    if (k0 < vlen) {
        const float* ekp = Ek + (size_t)b * HDIM * KLEN + k0;
        #pragma unroll 8
        for (int h = 0; h < HDIM; h++) {
            float2 ek = *(const float2*)(ekp + (size_t)h * KLEN);
            float4 e  = eqw[h];
            a00 = fmaf(e.z, __builtin_amdgcn_rcpf(fmaf(e.x, ek.x, 1.f)), a00);
            a01 = fmaf(e.z, __builtin_amdgcn_rcpf(fmaf(e.x, ek.y, 1.f)), a01);
            a10 = fmaf(e.z, __builtin_amdgcn_rcpf(fmaf(e.y, ek.x, 1.f)), a10);
            a11 = fmaf(e.z, __builtin_amdgcn_rcpf(fmaf(e.y, ek.y, 1.f)), a11);
        }
    }
    float s00 = (k0 < vlen)     ? a00 : -1e30f;
    float s01 = (k0 + 1 < vlen) ? a01 : -1e30f;
    float s10 = (k0 < vlen)     ? a10 : -1e30f;
    float s11 = (k0 + 1 < vlen) ? a11 : -1e30f;

    float m0 = fmaxf(s00, s01), m1 = fmaxf(s10, s11);
    #pragma unroll
    for (int off = 32; off > 0; off >>= 1) {
        m0 = fmaxf(m0, __shfl_xor(m0, off, 64));
        m1 = fmaxf(m1, __shfl_xor(m1, off, 64));
    }
    if (lane == 0) { red0[wav] = m0; red1[wav] = m1; }
    __syncthreads();
    m0 = red0[0]; m1 = red1[0];
    #pragma unroll
    for (int i = 1; i < 8; i++) {
        m0 = fmaxf(m0, red0[i]);
        m1 = fmaxf(m1, red1[i]);
    }

    float e00 = __expf(s00 - m0), e01 = __expf(s01 - m0);   // masked -> exact 0
    float e10 = __expf(s10 - m1), e11 = __expf(s11 - m1);
    float t0 = e00 + e01, t1 = e10 + e11;
    #pragma unroll
    for (int off = 32; off > 0; off >>= 1) {
        t0 += __shfl_xor(t0, off, 64);
        t1 += __shfl_xor(t1, off, 64);
    }
    __syncthreads();
    if (lane == 0) { red0[wav] = t0; red1[wav] = t1; }
    __syncthreads();
    t0 = red0[0]; t1 = red1[0];
    #pragma unroll
    for (int i = 1; i < 8; i++) { t0 += red0[i]; t1 += red1[i]; }
    float inv0 = 1.0f / t0, inv1 = 1.0f / t1;

    sc0[k0]     = e00 * inv0;
    sc0[k0 + 1] = e01 * inv0;
    sc1[k0]     = e10 * inv1;
    sc1[k0 + 1] = e11 * inv1;
    __syncthreads();

    // ---- Phase 2: AV. wave -> (q = wav&1, k-slice = wav>>1), lane -> d4 ----
    int q  = wav & 1;
    int ks = wav >> 1;
    int klo = ks << 8;
    float4 a = make_float4(0.f, 0.f, 0.f, 0.f);
    if (klo < vlen) {
        int kc = vlen - klo; kc = kc > 256 ? 256 : kc;
        int kcc = (kc + 3) & ~3;               // sc zero-padded -> safe round-up
        const float* sl = q ? sc1 : sc0;
        const float* vb = values + ((size_t)b * KLEN + klo) * DDIM + (lane << 2);
        #pragma unroll 4
        for (int k = 0; k < kcc; k += 4) {
            float4 pk = *(const float4*)(&sl[klo + k]);   // wave-uniform b128
            float4 v0 = *(const float4*)(vb + (size_t)(k + 0) * DDIM);
            float4 v1 = *(const float4*)(vb + (size_t)(k + 1) * DDIM);
            float4 v2 = *(const float4*)(vb + (size_t)(k + 2) * DDIM);
            float4 v3 = *(const float4*)(vb + (size_t)(k + 3) * DDIM);
            a.x = fmaf(pk.x, v0.x, a.x); a.y = fmaf(pk.x, v0.y, a.y);
            a.z = fmaf(pk.x, v0.z, a.z); a.w = fmaf(pk.x, v0.w, a.w);
            a.x = fmaf(pk.y, v1.x, a.x); a.y = fmaf(pk.y, v1.y, a.y);
            a.z = fmaf(pk.y, v1.z, a.z); a.w = fmaf(pk.y, v1.w, a.w);
            a.x = fmaf(pk.z, v2.x, a.x); a.y = fmaf(pk.z, v2.y, a.y);
            a.z = fmaf(pk.z, v2.z, a.z); a.w = fmaf(pk.z, v2.w, a.w);
            a.x = fmaf(pk.w, v3.x, a.x); a.y = fmaf(pk.w, v3.y, a.y);
            a.z = fmaf(pk.w, v3.z, a.z); a.w = fmaf(pk.w, v3.w, a.w);
        }
    }
    pb[ks][q][lane] = a;
    __syncthreads();

    if (tid < 128) {
        int qq = tid >> 6, d4 = tid & 63;
        float4 r0 = pb[0][qq][d4], r1 = pb[1][qq][d4];
        float4 r2 = pb[2][qq][d4], r3 = pb[3][qq][d4];
        float4 o = make_float4((r0.x + r1.x) + (r2.x + r3.x),
                               (r0.y + r1.y) + (r2.y + r3.y),
                               (r0.z + r1.z) + (r2.z + r3.z),
                               (r0.w + r1.w) + (r2.w + r3.w));
        *(float4*)(out + (size_t)(bq0 + qq) * DDIM + (d4 << 2)) = o;
    }
}

extern "C" void kernel_launch(void* const* d_in, const int* in_sizes, int n_in,
                              void* d_out, int out_size, void* d_ws, size_t ws_size,
                              hipStream_t stream) {
    const float* queries    = (const float*)d_in[0]; // [16,64,256]
    const float* keys       = (const float*)d_in[1]; // [16,1024,256]
    const float* values     = (const float*)d_in[2]; // [16,1024,256]
    const int*   valid_lens = (const int*)d_in[3];   // [16]
    const float* W_q        = (const float*)d_in[4]; // [256,128]
    const float* W_k        = (const float*)d_in[5]; // [256,128]
    const float* w_v        = (const float*)d_in[6]; // [128]

    float* Eq = (float*)d_ws;              // 1024*128     = 512 KB
    float* Ek = Eq + 131072;               // 16*128*1024  = 8 MB

    proj_kernel<<<544, 256, 0, stream>>>(queries, keys, W_q, W_k, Eq, Ek);
    attn_kernel<<<512, 512, 0, stream>>>(Eq, Ek, values, w_v, valid_lens,
                                         (float*)d_out);
}

// Round 12
// 172.804 us; speedup vs baseline: 1.0475x; 1.0475x over previous
//
#include <hip/hip_runtime.h>

#define DDIM 256
#define HDIM 128
#define KLEN 1024
#define SCL 2.8853900817779268f   // 2*log2(e): exp2(SCL*x) == e^{2x}
#define WSTR 132                  // wt row stride for 128-d half; mult of 4

// ============ Projection -> Eq/Ek = exp2(SCL * in@W) ============
// 32 rows x 64 h-half per block -> grid 1088 (4.25 blocks/CU; LDS 33.8 KB
// allows 4). Same W staging + 8:1 FMA:VMEM hot loop as r10.
__global__ __launch_bounds__(256) void proj_kernel(
    const float* __restrict__ queries, const float* __restrict__ keys,
    const float* __restrict__ W_q, const float* __restrict__ W_k,
    float* __restrict__ Eq, float* __restrict__ Ek)
{
    __shared__ union {
        float w[64 * WSTR];   // 33.8 KB: wt[h][d] = W[dt+d][hbase+h], d in [0,128)
        float t[64][33];      // keys transpose staging (epilogue only)
    } sm;

    int tid = threadIdx.x;
    int hg  = tid & 31;       // h index; owns hg and hg+32
    int rg  = tid >> 5;       // row-group (4 rows)
    int blk = blockIdx.x;

    const float* in; const float* W; int row0, hbase, b = 0, kc0 = 0; bool iskey;
    if (blk < 1024) {
        iskey = true;
        int xcd = blk & 7, s = blk >> 3;     // s 0..127
        b = ((s >= 64) ? 8 : 0) + xcd;       // batch b resident on XCD b&7
        int r = s & 63;                      // 32 k-tiles x 2 h-halves
        kc0   = (r >> 1) * 32;
        hbase = (r & 1) << 6;
        row0  = b * KLEN + kc0;
        in = keys; W = W_k;
    } else {
        iskey = false;
        int qi = blk - 1024;                 // 0..63
        row0  = (qi >> 1) * 32;
        hbase = (qi & 1) << 6;
        in = queries; W = W_q;
    }

    const float* r0p = in + (size_t)(row0 + rg * 4) * DDIM;
    float2 acc[4];
    #pragma unroll
    for (int j = 0; j < 4; j++) acc[j] = make_float2(0.f, 0.f);

    for (int dt = 0; dt < DDIM; dt += 128) {
        __syncthreads();
        {   // stage W[dt..dt+127][hbase..+63] -> wt[h][d] (4x4 register transpose)
            int d4g = tid >> 4;            // 0..15
            int hl  = (tid & 15) << 2;     // 0..60
            #pragma unroll
            for (int i = 0; i < 2; i++) {
                int d = i * 64 + d4g * 4;
                const float* wg = W + (size_t)(dt + d) * HDIM + hbase + hl;
                float4 g0 = *(const float4*)(wg);
                float4 g1 = *(const float4*)(wg + HDIM);
                float4 g2 = *(const float4*)(wg + 2 * HDIM);
                float4 g3 = *(const float4*)(wg + 3 * HDIM);
                *(float4*)(&sm.w[(hl + 0) * WSTR + d]) = make_float4(g0.x, g1.x, g2.x, g3.x);
                *(float4*)(&sm.w[(hl + 1) * WSTR + d]) = make_float4(g0.y, g1.y, g2.y, g3.y);
                *(float4*)(&sm.w[(hl + 2) * WSTR + d]) = make_float4(g0.z, g1.z, g2.z, g3.z);
                *(float4*)(&sm.w[(hl + 3) * WSTR + d]) = make_float4(g0.w, g1.w, g2.w, g3.w);
            }
        }
        __syncthreads();

        const float* wp0 = &sm.w[(size_t)hg * WSTR];
        const float* wp1 = &sm.w[(size_t)(hg + 32) * WSTR];
        #pragma unroll 4
        for (int d0 = 0; d0 < 128; d0 += 4) {
            float4 w0 = *(const float4*)(wp0 + d0);
            float4 w1 = *(const float4*)(wp1 + d0);
            #pragma unroll
            for (int j = 0; j < 4; j++) {
                float4 a = *(const float4*)(r0p + (size_t)j * DDIM + dt + d0);
                acc[j].x = fmaf(a.x, w0.x, acc[j].x); acc[j].y = fmaf(a.x, w1.x, acc[j].y);
                acc[j].x = fmaf(a.y, w0.y, acc[j].x); acc[j].y = fmaf(a.y, w1.y, acc[j].y);
                acc[j].x = fmaf(a.z, w0.z, acc[j].x); acc[j].y = fmaf(a.z, w1.z, acc[j].y);
                acc[j].x = fmaf(a.w, w0.w, acc[j].x); acc[j].y = fmaf(a.w, w1.w, acc[j].y);
            }
        }
    }

    if (!iskey) {
        #pragma unroll
        for (int j = 0; j < 4; j++) {
            float* er = Eq + (size_t)(row0 + rg * 4 + j) * HDIM + hbase;
            er[hg]      = __builtin_amdgcn_exp2f(SCL * acc[j].x);
            er[hg + 32] = __builtin_amdgcn_exp2f(SCL * acc[j].y);
        }
    } else {
        __syncthreads();
        #pragma unroll
        for (int j = 0; j < 4; j++) {
            int kl = rg * 4 + j;
            sm.t[hg][kl]      = __builtin_amdgcn_exp2f(SCL * acc[j].x);
            sm.t[hg + 32][kl] = __builtin_amdgcn_exp2f(SCL * acc[j].y);
        }
        __syncthreads();
        float* dst = Ek + (size_t)b * HDIM * KLEN + (size_t)hbase * KLEN + kc0;
        #pragma unroll
        for (int ii = 0; ii < 2; ii++) {
            int i2 = tid + 256 * ii;           // 512 float4 slots: 64 h x 32 k
            int hh = i2 >> 3, c = (i2 & 7) << 2;
            float4 o = make_float4(sm.t[hh][c], sm.t[hh][c + 1],
                                   sm.t[hh][c + 2], sm.t[hh][c + 3]);
            *(float4*)(dst + (size_t)hh * KLEN + c) = o;
        }
    }
}

// ============ Raw scores, split-k ============
// Grid 512 (XCD-swizzled) = (b, 4q-tile, k-half). 256 threads, thread = 2k x 4q.
// Each Ek element serves 4 queries (traffic 256->128 MB). Writes raw scores
// (masked k -> -1e30) to S; softmax_kernel normalizes in place.
__global__ __launch_bounds__(256) void scoreS_kernel(
    const float* __restrict__ Eq, const float* __restrict__ Ek,
    const float* __restrict__ w_v, const int* __restrict__ valid_lens,
    float* __restrict__ S)
{
    __shared__ float4 eq4[HDIM];
    __shared__ float  w2l[HDIM];

    int tid = threadIdx.x;
    int blk = blockIdx.x;
    int xcd = blk & 7, s = blk >> 3;
    int b = ((s >= 32) ? 8 : 0) + xcd;
    int r = s & 31;
    int qt = r >> 1, kh = r & 1;
    int bq0 = b * 64 + qt * 4;
    int kbeg = kh << 9;
    int vlen = valid_lens[b];

    if (tid < HDIM) {
        eq4[tid] = make_float4(Eq[(size_t)(bq0 + 0) * HDIM + tid],
                               Eq[(size_t)(bq0 + 1) * HDIM + tid],
                               Eq[(size_t)(bq0 + 2) * HDIM + tid],
                               Eq[(size_t)(bq0 + 3) * HDIM + tid]);
        w2l[tid] = -2.0f * w_v[tid];
    }
    __syncthreads();

    int k0 = kbeg + (tid << 1);
    float a[8];
    #pragma unroll
    for (int i = 0; i < 8; i++) a[i] = 0.f;

    if (k0 < vlen) {
        const float* ekp = Ek + (size_t)b * HDIM * KLEN + k0;
        #pragma unroll 8
        for (int h = 0; h < HDIM; h++) {
            float2 ek = *(const float2*)(ekp + (size_t)h * KLEN);
            float4 e  = eq4[h];
            float w2  = w2l[h];
            a[0] = fmaf(w2, __builtin_amdgcn_rcpf(fmaf(e.x, ek.x, 1.f)), a[0]);
            a[1] = fmaf(w2, __builtin_amdgcn_rcpf(fmaf(e.x, ek.y, 1.f)), a[1]);
            a[2] = fmaf(w2, __builtin_amdgcn_rcpf(fmaf(e.y, ek.x, 1.f)), a[2]);
            a[3] = fmaf(w2, __builtin_amdgcn_rcpf(fmaf(e.y, ek.y, 1.f)), a[3]);
            a[4] = fmaf(w2, __builtin_amdgcn_rcpf(fmaf(e.z, ek.x, 1.f)), a[4]);
            a[5] = fmaf(w2, __builtin_amdgcn_rcpf(fmaf(e.z, ek.y, 1.f)), a[5]);
            a[6] = fmaf(w2, __builtin_amdgcn_rcpf(fmaf(e.w, ek.x, 1.f)), a[6]);
            a[7] = fmaf(w2, __builtin_amdgcn_rcpf(fmaf(e.w, ek.y, 1.f)), a[7]);
        }
    }
    bool v0 = k0 < vlen, v1 = (k0 + 1) < vlen;
    #pragma unroll
    for (int q = 0; q < 4; q++) {
        float2 o = make_float2(v0 ? a[2 * q + 0] : -1e30f,
                               v1 ? a[2 * q + 1] : -1e30f);
        *(float2*)(S + (size_t)(bq0 + q) * KLEN + k0) = o;
    }
}

// ============ In-place masked softmax over S rows ============
// Grid 1024 (XCD-swizzled) = (b,q). 256 threads, 4 k each. Masked (-1e30)
// slots come out exactly 0.
__global__ __launch_bounds__(256) void softmax_kernel(float* __restrict__ S)
{
    __shared__ float red[8];
    int tid = threadIdx.x, lane = tid & 63, wav = tid >> 6;
    int blk = blockIdx.x;
    int xcd = blk & 7, s = blk >> 3;
    int b = ((s >= 64) ? 8 : 0) + xcd;
    int q = s & 63;
    float* row = S + (size_t)(b * 64 + q) * KLEN;

    float s0 = row[tid], s1 = row[tid + 256], s2 = row[tid + 512], s3 = row[tid + 768];
    float m = fmaxf(fmaxf(s0, s1), fmaxf(s2, s3));
    #pragma unroll
    for (int off = 32; off > 0; off >>= 1) m = fmaxf(m, __shfl_xor(m, off, 64));
    if (lane == 0) red[wav] = m;
    __syncthreads();
    m = fmaxf(fmaxf(red[0], red[1]), fmaxf(red[2], red[3]));

    float e0 = __expf(s0 - m), e1 = __expf(s1 - m);
    float e2 = __expf(s2 - m), e3 = __expf(s3 - m);
    float t = (e0 + e1) + (e2 + e3);
    #pragma unroll
    for (int off = 32; off > 0; off >>= 1) t += __shfl_xor(t, off, 64);
    __syncthreads();
    if (lane == 0) red[4 + wav] = t;
    __syncthreads();
    float inv = 1.0f / (red[4] + red[5] + red[6] + red[7]);

    row[tid]       = e0 * inv;
    row[tid + 256] = e1 * inv;
    row[tid + 512] = e2 * inv;
    row[tid + 768] = e3 * inv;
}

// ============ attn @ V (r10 structure) ============
// Grid 512 = (16 b XCD-swizzled) x (8 q-tiles of 8) x (4 k-quarters of 256).
// 512 threads: wave = (q-pair, k-128-half); p-tile [256k][8q] in 10 KB LDS.
__global__ __launch_bounds__(512) void av_kernel(
    const float* __restrict__ p, const float* __restrict__ values,
    const int* __restrict__ valid_lens, float* __restrict__ part)
{
    __shared__ float pt[256][10];

    int blk = blockIdx.x;
    int xcd = blk & 7, s = blk >> 3;
    int b = ((s >= 32) ? 8 : 0) + xcd;
    int r = s & 31, qt = r >> 2, kq = r & 3;
    int tid = threadIdx.x, lane = tid & 63, w = tid >> 6;
    int qp = w & 3, kh = w >> 2;
    int vlen = valid_lens[b];
    int kbeg = kq << 8;
    int bq0 = b * 64 + qt * 8;

    {   // stage p[8q][256k] -> pt[k][q]
        int q = tid >> 6, k4 = (tid & 63) << 2;
        float4 pv = *(const float4*)(p + (size_t)(bq0 + q) * KLEN + kbeg + k4);
        pt[k4 + 0][q] = pv.x;
        pt[k4 + 1][q] = pv.y;
        pt[k4 + 2][q] = pv.z;
        pt[k4 + 3][q] = pv.w;
    }
    __syncthreads();

    int klo = kh << 7;
    int kcw = vlen - (kbeg + klo);
    kcw = kcw < 0 ? 0 : (kcw > 128 ? 128 : kcw);
    int kcc = (kcw + 31) & ~31;              // p==0 beyond vlen -> safe round-up

    const float* vb = values + ((size_t)b * KLEN + kbeg + klo) * DDIM + (lane << 2);
    float4 a0 = make_float4(0.f, 0.f, 0.f, 0.f);
    float4 a1 = make_float4(0.f, 0.f, 0.f, 0.f);

    for (int kt = 0; kt < kcc; kt += 32) {
        #pragma unroll
        for (int k2 = 0; k2 < 32; k2++) {
            int k = kt + k2;
            float2 pp = *(const float2*)(&pt[klo + k][qp << 1]);
            float4 v  = *(const float4*)(vb + (size_t)k * DDIM);
            a0.x = fmaf(pp.x, v.x, a0.x); a0.y = fmaf(pp.x, v.y, a0.y);
            a0.z = fmaf(pp.x, v.z, a0.z); a0.w = fmaf(pp.x, v.w, a0.w);
            a1.x = fmaf(pp.y, v.x, a1.x); a1.y = fmaf(pp.y, v.y, a1.y);
            a1.z = fmaf(pp.y, v.z, a1.z); a1.w = fmaf(pp.y, v.w, a1.w);
        }
    }
    int ks = (kq << 1) + kh;
    float* d0 = part + ((size_t)ks * 1024 + bq0 + (qp << 1)) * DDIM + (lane << 2);
    *(float4*)(d0)        = a0;
    *(float4*)(d0 + DDIM) = a1;
}

// ============ sum 8 k-partials ============
__global__ __launch_bounds__(256) void combine_kernel(
    const float* __restrict__ part, float* __restrict__ out)
{
    int i = blockIdx.x * 256 + threadIdx.x;        // 65536 float4 slots
    const float4* p4 = (const float4*)part;
    float4 a = p4[i];
    #pragma unroll
    for (int j = 1; j < 8; j++) {
        float4 v = p4[(size_t)j * 65536 + i];
        a.x += v.x; a.y += v.y; a.z += v.z; a.w += v.w;
    }
    ((float4*)out)[i] = a;
}

extern "C" void kernel_launch(void* const* d_in, const int* in_sizes, int n_in,
                              void* d_out, int out_size, void* d_ws, size_t ws_size,
                              hipStream_t stream) {
    const float* queries    = (const float*)d_in[0]; // [16,64,256]
    const float* keys       = (const float*)d_in[1]; // [16,1024,256]
    const float* values     = (const float*)d_in[2]; // [16,1024,256]
    const int*   valid_lens = (const int*)d_in[3];   // [16]
    const float* W_q        = (const float*)d_in[4]; // [256,128]
    const float* W_k        = (const float*)d_in[5]; // [256,128]
    const float* w_v        = (const float*)d_in[6]; // [128]

    float* Eq   = (float*)d_ws;            // 1024*128     = 512 KB
    float* Ek   = Eq + 131072;             // 16*128*1024  = 8 MB
    float* S    = Ek + 2097152;            // 1024*1024    = 4 MB (raw -> p in place)
    float* part = Ek;                      // alias: Ek dead after scoreS; 8 MB exact

    proj_kernel<<<1088, 256, 0, stream>>>(queries, keys, W_q, W_k, Eq, Ek);
    scoreS_kernel<<<512, 256, 0, stream>>>(Eq, Ek, w_v, valid_lens, S);
    softmax_kernel<<<1024, 256, 0, stream>>>(S);
    av_kernel<<<512, 512, 0, stream>>>(S, values, valid_lens, part);
    combine_kernel<<<256, 256, 0, stream>>>(part, (float*)d_out);
}